// Round 1
// 620.754 us; speedup vs baseline: 1.0658x; 1.0658x over previous
//
#include <hip/hip_runtime.h>
#include <math.h>

// Problem constants
#define NTOK 4096      // B*T
#define DIM  1024
#define NE   8
#define FF   4096

// d_out layout (floats): output | gate_logits | topk_idx | expert_counts
#define OUT_LOGITS 4194304
#define OUT_IDX    4227072
#define OUT_CNT    4235264

typedef unsigned short u16;
typedef __bf16 bf16x8 __attribute__((ext_vector_type(8)));
typedef float  f32x4  __attribute__((ext_vector_type(4)));

__device__ __forceinline__ u16 f2bf(float f) {
  union { float f; unsigned u; } v; v.f = f;
  unsigned r = v.u + 0x7fffu + ((v.u >> 16) & 1u);
  return (u16)(r >> 16);
}

__device__ __forceinline__ float gelu_f(float v) {
  // tanh-approx gelu; |err| vs exact < ~3e-3 absolute, well under 2% threshold
  float u = v * (0.7978845608f + 0.0356774081f * v * v);
  float e = __expf(2.f * u);
  float t = 1.f - 2.f / (e + 1.f);
  return 0.5f * v * (1.f + t);
}

__device__ __forceinline__ void gload_lds16(const u16* g, u16* l) {
  __builtin_amdgcn_global_load_lds(
      (const __attribute__((address_space(1))) void*)(g),
      (__attribute__((address_space(3))) void*)(l), 16, 0, 0);
}

// ---------------- transpose + convert: in[R][C] f32 -> out[C][R] bf16, per expert z ----------------
__global__ __launch_bounds__(256) void transpose_cvt_kernel(const float* __restrict__ in,
                                                            u16* __restrict__ out,
                                                            int R, int C) {
  __shared__ float tile[64][68];   // stride 68: 16B-aligned rows, 2-way-max read banks
  in  += (size_t)blockIdx.z * R * C;
  out += (size_t)blockIdx.z * R * C;
  int c0 = blockIdx.x * 64, r0 = blockIdx.y * 64;
  int t = threadIdx.x;
  int cr = (t & 15) * 4, rr = t >> 4;
  #pragma unroll
  for (int p = 0; p < 4; p++) {
    float4 v = *(const float4*)(in + (size_t)(r0 + rr + p * 16) * C + c0 + cr);
    *(float4*)&tile[rr + p * 16][cr] = v;
  }
  __syncthreads();
  int c = t >> 2, rb = (t & 3) * 4;
  u16* orow = out + (size_t)(c0 + c) * R + r0;
  #pragma unroll
  for (int it = 0; it < 4; it++) {
    int r = it * 16 + rb;
    ushort4 o;
    o.x = f2bf(tile[r + 0][c]);
    o.y = f2bf(tile[r + 1][c]);
    o.z = f2bf(tile[r + 2][c]);
    o.w = f2bf(tile[r + 3][c]);
    *(ushort4*)(orow + r) = o;
  }
}

// ---------------- gate: fp32 logits, top-2, softmax; NO atomics ----------------
__global__ __launch_bounds__(256) void gate_kernel(const float* __restrict__ x,
                                                   const float* __restrict__ gw,
                                                   const float* __restrict__ gb,
                                                   float* __restrict__ out,
                                                   int2* __restrict__ tk_idx,
                                                   float2* __restrict__ tk_w) {
  int wave = threadIdx.x >> 6, lane = threadIdx.x & 63;
  int token = blockIdx.x * 4 + wave;
  const float* xr = x + (size_t)token * DIM + lane * 16;
  float acc[NE];
  #pragma unroll
  for (int e = 0; e < NE; e++) acc[e] = 0.f;
  #pragma unroll
  for (int c = 0; c < 16; c += 4) {
    float4 xv = *(const float4*)(xr + c);
    const float* gwr = gw + (size_t)(lane * 16 + c) * NE;
    float xs[4] = {xv.x, xv.y, xv.z, xv.w};
    #pragma unroll
    for (int q = 0; q < 4; q++)
      #pragma unroll
      for (int e = 0; e < NE; e++)
        acc[e] += xs[q] * gwr[q * NE + e];
  }
  #pragma unroll
  for (int off = 32; off; off >>= 1)
    #pragma unroll
    for (int e = 0; e < NE; e++)
      acc[e] += __shfl_down(acc[e], off);

  if (lane == 0) {
    float lg[NE];
    #pragma unroll
    for (int e = 0; e < NE; e++) {
      lg[e] = acc[e] + gb[e];
      out[OUT_LOGITS + token * NE + e] = lg[e];
    }
    int i0 = 0; float v0 = lg[0];
    #pragma unroll
    for (int e = 1; e < NE; e++) if (lg[e] > v0) { v0 = lg[e]; i0 = e; }
    int i1 = -1; float v1 = -1e30f;
    #pragma unroll
    for (int e = 0; e < NE; e++) if (e != i0 && lg[e] > v1) { v1 = lg[e]; i1 = e; }
    float ex = expf(v1 - v0);
    float s = 1.f + ex;
    out[OUT_IDX + token * 2]     = (float)i0;
    out[OUT_IDX + token * 2 + 1] = (float)i1;
    tk_idx[token] = make_int2(i0, i1);
    tk_w[token]   = make_float2(1.f / s, ex / s);
  }
}

// ---------------- build flat routing lists: 1 block, wave e compacts expert e ----------------
__global__ __launch_bounds__(512) void build_lists_kernel(
    const int2* __restrict__ tk_idx, const float2* __restrict__ tk_w,
    int* __restrict__ counts, int* __restrict__ offsets,
    int* __restrict__ tok_list, float* __restrict__ wt_list,
    float* __restrict__ cnt_out) {
  __shared__ int s_cnt[NE];
  int e = threadIdx.x >> 6, lane = threadIdx.x & 63;
  // phase 1: count
  int cnt = 0;
  for (int base = 0; base < NTOK; base += 64) {
    int2 idx = tk_idx[base + lane];
    cnt += __popcll(__ballot(idx.x == e || idx.y == e));
  }
  if (lane == 0) s_cnt[e] = cnt;
  __syncthreads();
  int off = 0;
  for (int ee = 0; ee < e; ee++) off += s_cnt[ee];
  if (lane == 0) {
    counts[e]  = s_cnt[e];
    offsets[e] = off;
    cnt_out[e] = (float)s_cnt[e];
  }
  // phase 2: emit (deterministic, ordered by token)
  int pos = off;
  for (int base = 0; base < NTOK; base += 64) {
    int tok = base + lane;
    int2 idx = tk_idx[tok];
    float2 w = tk_w[tok];
    bool m0 = (idx.x == e), m1 = (idx.y == e);
    bool m = m0 || m1;
    unsigned long long mask = __ballot(m);
    if (m) {
      int p = pos + __popcll(mask & ((1ull << lane) - 1ull));
      tok_list[p] = tok;
      wt_list[p]  = m0 ? w.x : w.y;
    }
    pos += __popcll(mask);
  }
}

// ---------------- gather + convert: xg[slot][:] = bf16(x[tok_list[slot]][:]) ----------------
__global__ __launch_bounds__(256) void gather_x_kernel(const float* __restrict__ x,
                                                       const int* __restrict__ tok_list,
                                                       u16* __restrict__ xg) {
  int g = blockIdx.x;
  int tok = tok_list[g];
  int c = threadIdx.x * 4;
  float4 v = *(const float4*)(x + (size_t)tok * DIM + c);
  ushort4 o;
  o.x = f2bf(v.x); o.y = f2bf(v.y); o.z = f2bf(v.z); o.w = f2bf(v.w);
  *(ushort4*)(xg + (size_t)g * DIM + c) = o;
}

// ---------------- MoE GEMM v2: 2-phase prefetch (T3-min), BK=64, 8 waves, T2 swizzle ----------
// MODE 0: xg[slot][DIM] x w1t[e][FF][DIM] -> h (gelu, bf16)
// MODE 1: h[slot][FF]   x w2t[e][DIM][FF] -> out (scaled atomic f32)
// LDS swizzle (T2, rule #21 both-sides): physical chunk c of row holds logical chunk
// c ^ (row&7). Applied on the GLOBAL source address at staging (gload_lds dest stays
// linear, as required) and on the ds_read address. 16 l16-lanes then hit 8 distinct
// 16B slots -> 2-way (free) instead of 16-way conflicts.
template <int MODE, int BM, int BN>
__global__ __launch_bounds__(512, 2) void moe_gemm2_kernel(
    const u16* __restrict__ Abase, const u16* __restrict__ Bbase,
    const float* __restrict__ bias,
    const int* __restrict__ counts, const int* __restrict__ offsets,
    const int* __restrict__ tok_list, const float* __restrict__ wt_list,
    u16* __restrict__ Hout, float* __restrict__ Out) {
  constexpr int KT = (MODE == 0) ? DIM : FF;   // reduction length
  constexpr int NT = (MODE == 0) ? FF : DIM;   // output width
  constexpr int LA = BM / 64;                  // A gloads / thread / K-tile
  constexpr int LB = BN / 64;                  // B gloads / thread / K-tile
  constexpr int MR = BM / 32;                  // M frags per wave (2 M-waves)
  constexpr int NR = BN / 64;                  // N frags per wave (4 N-waves)
  constexpr int ASZ = BM * 64;                 // u16 per A buffer
  constexpr int BSZ = BN * 64;
  constexpr int NTILES = KT / 64;

  extern __shared__ u16 sm[];                  // [2*ASZ + 2*BSZ]

  const int e  = blockIdx.z;
  const int ne = counts[e];
  const int m0 = blockIdx.y * BM;
  if (m0 >= ne) return;
  const int n0   = blockIdx.x * BN;
  const int offs = offsets[e];

  const int t = threadIdx.x;
  const int wave = t >> 6, lane = t & 63;
  const int quad = lane >> 4, l16 = lane & 15;
  const int wmb = (wave & 1) * (BM / 2);
  const int wnb = (wave >> 1) * (BN / 4);

  // ---- staging pointers (global source pre-swizzled; LDS dest linear in thread id) ----
  const u16* aptr[LA];
  const u16* bptr[LB];
  #pragma unroll
  for (int p = 0; p < LA; p++) {
    int idx = p * 512 + t;
    int row = idx >> 3, c = idx & 7;
    int clog = c ^ (row & 7);
    int s = m0 + row; if (s > ne - 1) s = ne - 1;   // clamped gather (dup last row)
    aptr[p] = Abase + (size_t)(offs + s) * KT + clog * 8;
  }
  #pragma unroll
  for (int p = 0; p < LB; p++) {
    int idx = p * 512 + t;
    int row = idx >> 3, c = idx & 7;
    int clog = c ^ (row & 7);
    bptr[p] = Bbase + ((size_t)e * NT + n0 + row) * KT + clog * 8;
  }

  auto stage = [&](int buf, int k0) {
    #pragma unroll
    for (int p = 0; p < LA; p++)
      gload_lds16(aptr[p] + k0, sm + buf * ASZ + (p * 512 + t) * 8);
    #pragma unroll
    for (int p = 0; p < LB; p++)
      gload_lds16(bptr[p] + k0, sm + 2 * ASZ + buf * BSZ + (p * 512 + t) * 8);
  };

  // ---- loop-invariant fragment read offsets (u16 units) ----
  // row&7 == l16&7 for all frag rows (wmb, wnb, i*16 are multiples of 8)
  const int xrow = l16 & 7;
  const int xo[2] = { ((0 + quad) ^ xrow) * 8, ((4 + quad) ^ xrow) * 8 };
  const int abase0 = (wmb + l16) * 64;              // + i*1024 + xo[kk]
  const int bbase0 = 2 * ASZ + (wnb + l16) * 64;    // + j*1024 + xo[kk]

  f32x4 acc[MR][NR];
  #pragma unroll
  for (int i = 0; i < MR; i++)
    #pragma unroll
    for (int j = 0; j < NR; j++)
      acc[i][j] = (f32x4){0.f, 0.f, 0.f, 0.f};

  // ---- 2-phase main loop: issue next-tile stage, compute current, ONE vmcnt(0)+barrier ----
  stage(0, 0);
  __syncthreads();
  int cur = 0;
  for (int kt = 0; kt < NTILES; ++kt) {
    if (kt + 1 < NTILES) stage(cur ^ 1, (kt + 1) * 64);
    const u16* As = sm + cur * ASZ;
    const u16* Bs = sm + cur * BSZ;   // bbase0 already includes the 2*ASZ offset
    #pragma unroll
    for (int kk = 0; kk < 2; kk++) {
      bf16x8 a[MR], b[NR];
      #pragma unroll
      for (int i = 0; i < MR; i++) a[i] = *(const bf16x8*)&As[abase0 + i * 1024 + xo[kk]];
      #pragma unroll
      for (int j = 0; j < NR; j++) b[j] = *(const bf16x8*)&Bs[bbase0 + j * 1024 + xo[kk]];
      #pragma unroll
      for (int i = 0; i < MR; i++)
        #pragma unroll
        for (int j = 0; j < NR; j++)
          acc[i][j] = __builtin_amdgcn_mfma_f32_16x16x32_bf16(a[i], b[j], acc[i][j], 0, 0, 0);
    }
    __syncthreads();   // drains vmcnt(0) (next-tile stage) + lgkmcnt; then barrier
    cur ^= 1;
  }

  // ---- epilogue ----
  if (MODE == 0) {
    const float* bb = bias + (size_t)e * FF + n0 + wnb;
    float bc[NR];
    #pragma unroll
    for (int j = 0; j < NR; j++) bc[j] = bb[j * 16 + l16];
    #pragma unroll
    for (int i = 0; i < MR; i++) {
      #pragma unroll
      for (int r = 0; r < 4; r++) {
        int s = m0 + wmb + i * 16 + quad * 4 + r;
        if (s < ne) {
          u16* hr = Hout + (size_t)(offs + s) * FF + n0 + wnb;
          #pragma unroll
          for (int j = 0; j < NR; j++)
            hr[j * 16 + l16] = f2bf(gelu_f(acc[i][j][r] + bc[j]));
        }
      }
    }
  } else {
    const float* bb = bias + (size_t)e * DIM + n0 + wnb;
    float bc[NR];
    #pragma unroll
    for (int j = 0; j < NR; j++) bc[j] = bb[j * 16 + l16];
    #pragma unroll
    for (int i = 0; i < MR; i++) {
      #pragma unroll
      for (int r = 0; r < 4; r++) {
        int s = m0 + wmb + i * 16 + quad * 4 + r;
        if (s < ne) {
          int   tok = tok_list[offs + s];
          float w   = wt_list[offs + s];
          float* orow = Out + (size_t)tok * DIM + n0 + wnb;
          #pragma unroll
          for (int j = 0; j < NR; j++)
            atomicAdd(&orow[j * 16 + l16], (acc[i][j][r] + bc[j]) * w);
        }
      }
    }
  }
}

extern "C" void kernel_launch(void* const* d_in, const int* in_sizes, int n_in,
                              void* d_out, int out_size, void* d_ws, size_t ws_size,
                              hipStream_t stream) {
  const float* x   = (const float*)d_in[0];
  const float* gw  = (const float*)d_in[1];
  const float* gb  = (const float*)d_in[2];
  const float* w1  = (const float*)d_in[3];
  const float* b1  = (const float*)d_in[4];
  const float* w2  = (const float*)d_in[5];
  const float* b2  = (const float*)d_in[6];
  float* out = (float*)d_out;
  char*  ws  = (char*)d_ws;

  // ws layout
  u16* w1t = (u16*)(ws);                                    // 64 MB  [E][FF][DIM]
  u16* w2t = (u16*)(ws + 1ull * 67108864);                  // 64 MB  [E][DIM][FF]
  u16* h   = (u16*)(ws + 2ull * 67108864);                  // 64 MB  [8192][FF]
  u16* xg  = (u16*)(ws + 3ull * 67108864);                  // 16 MB  [8192][DIM]
  char* meta = ws + 3ull * 67108864 + 16777216;
  int*    counts   = (int*)(meta);
  int*    offsets  = (int*)(meta + 64);
  int*    tok_list = (int*)(meta + 128);                    // flat [8192]
  float*  wt_list  = (float*)(meta + 128 + 32768);          // flat [8192]
  int2*   tk_idx   = (int2*)(meta + 128 + 2 * 32768);       // [4096]
  float2* tk_w     = (float2*)(meta + 128 + 2 * 32768 + 32768);
  (void)in_sizes; (void)n_in; (void)out_size; (void)ws_size;

  // dynamic-LDS opt-in (>64KB); host-side, not a stream op (graph-capture safe)
  static bool attr_set = false;
  if (!attr_set) {
    hipFuncSetAttribute(reinterpret_cast<const void*>(moe_gemm2_kernel<0, 256, 256>),
                        hipFuncAttributeMaxDynamicSharedMemorySize, 131072);
    hipFuncSetAttribute(reinterpret_cast<const void*>(moe_gemm2_kernel<1, 128, 256>),
                        hipFuncAttributeMaxDynamicSharedMemorySize, 98304);
    attr_set = true;
  }

  hipMemsetAsync(out, 0, (size_t)OUT_LOGITS * 4, stream);   // zero main output (atomics accumulate)

  transpose_cvt_kernel<<<dim3(FF / 64, DIM / 64, NE), 256, 0, stream>>>(w1, w1t, DIM, FF);
  transpose_cvt_kernel<<<dim3(DIM / 64, FF / 64, NE), 256, 0, stream>>>(w2, w2t, FF, DIM);
  gate_kernel<<<NTOK / 4, 256, 0, stream>>>(x, gw, gb, out, tk_idx, tk_w);
  build_lists_kernel<<<1, 512, 0, stream>>>(tk_idx, tk_w, counts, offsets, tok_list, wt_list,
                                            out + OUT_CNT);
  gather_x_kernel<<<2 * NTOK, 256, 0, stream>>>(x, tok_list, xg);

  // GEMM1: M=slots(~8192 over experts), N=4096, K=1024 -> 256x256 tiles
  moe_gemm2_kernel<0, 256, 256><<<dim3(FF / 256, NTOK / 256, NE), 512, 131072, stream>>>(
      xg, w1t, b1, counts, offsets, tok_list, wt_list, h, nullptr);
  // GEMM2: M=slots, N=1024, K=4096 -> 128x256 tiles (keeps >=256 active blocks)
  moe_gemm2_kernel<1, 128, 256><<<dim3(DIM / 256, NTOK / 128, NE), 512, 98304, stream>>>(
      h, w2t, b2, counts, offsets, tok_list, wt_list, nullptr, out);
}